// Round 12
// baseline (182.680 us; speedup 1.0000x reference)
//
#include <hip/hip_runtime.h>
#include <hip/hip_bf16.h>

// Float inputs/outputs FP32; intermediates packed-bf16 (uint4).
// r27 (169.4): build-interleave in prep. r28 (165.7): W2 reg-double-buffer.
// r29 (163.4): interleave everywhere (prep half-1 regs, gather-head entry
// prefetch, pool score hoist). Top-5 = harness re-poison fills only.
// r30 (this round): cross-kernel XCD locality + u16 adjacency.
//  - prep XCD-swizzled: graph g's 8 blocks on residue g>>4 == agg1/gemm2s's
//    map -> h1u/adj/cnt produced in the SAME L2 their consumers read; cnt
//    atomics single-XCD.
//  - adj = u16 LOCAL ids (12.6->6.3MB): halved scattered stores in prep,
//    16-entry (one uint4 pair) register prefetch covers ~97% of rows.
//  - gather order per row unchanged (quads->a0/a1r/a2r/a3r, tail->a0).

#define BB 128
#define NN 512
#define NODES (BB*NN)          // 65536
#define EE (BB*NN*8)           // 524288
#define EDGPG (NN*8)           // 4096 edges per graph
#define F_IN 128
#define H1 64
#define H2 128
#define NC 10
#define KSEL 410
#define ROWCAP 48              // 1 self + up to 47 edges; P(indeg>=47) ~ 1e-22

typedef unsigned short u16;
typedef unsigned int   u32;

static __device__ __forceinline__ float lo2f(u32 u){ return __uint_as_float(u << 16); }
static __device__ __forceinline__ float hi2f(u32 u){ return __uint_as_float(u & 0xffff0000u); }
static __device__ __forceinline__ u16 f2b(float f){
    __hip_bfloat16 h = __float2bfloat16(f);   // RNE
    return *reinterpret_cast<u16*>(&h);
}
static __device__ __forceinline__ u32 packbf(float a, float b){
    return (u32)f2b(a) | ((u32)f2b(b) << 16);
}
static __device__ __forceinline__ void acc8s(float* a, uint4 v, float ds){
    a[0] = fmaf(ds, lo2f(v.x), a[0]); a[1] = fmaf(ds, hi2f(v.x), a[1]);
    a[2] = fmaf(ds, lo2f(v.y), a[2]); a[3] = fmaf(ds, hi2f(v.y), a[3]);
    a[4] = fmaf(ds, lo2f(v.z), a[4]); a[5] = fmaf(ds, hi2f(v.z), a[5]);
    a[6] = fmaf(ds, lo2f(v.w), a[6]); a[7] = fmaf(ds, hi2f(v.w), a[7]);
}
static __device__ __forceinline__ void acc8(float* a, uint4 v){
    a[0] += lo2f(v.x); a[1] += hi2f(v.x);
    a[2] += lo2f(v.y); a[3] += hi2f(v.y);
    a[4] += lo2f(v.z); a[5] += hi2f(v.z);
    a[6] += lo2f(v.w); a[7] += hi2f(v.w);
}
// XCD maps (all consistent: graph g -> hw residue g>>4):
static __device__ __forceinline__ int swz2048(int bid){   // 16 blk/graph
    return ((bid & 7) << 8) | (bid >> 3);
}
static __device__ __forceinline__ int swz1024(int bid){   // 8 blk/graph (prep)
    return ((bid & 7) << 7) | (bid >> 3);
}

// edge_index may arrive as int64 (odd 32-bit words all zero) or int32.
static __device__ __forceinline__ bool ei_is_i64(const int* __restrict__ ei){
    return ((ei[1] | ei[3] | ei[5] | ei[7]) == 0);
}
static __device__ __forceinline__ int ld_src(const int* __restrict__ ei, int e, bool w64){
    return w64 ? ei[2*e] : ei[e];
}
static __device__ __forceinline__ int ld_dst(const int* __restrict__ ei, int e, bool w64){
    return w64 ? ei[2*(EE + e)] : ei[EE + e];
}

// ---- K1: build (INTERLEAVED) + gemm1, half-1 reg-dbuf, XCD-swizzled ----
#define G1NODES 64
#define XPAD 68
__global__ __launch_bounds__(512) void k_prep_gemm1(const int* __restrict__ ei,
                                                    const float* __restrict__ x,
                                                    const float* __restrict__ W1,
                                                    int* __restrict__ cnt,
                                                    u16* __restrict__ adj,
                                                    u32* __restrict__ h1u){
    __shared__ __align__(16) float Ws[64*H1];          // 16 KB (one k-half)
    __shared__ __align__(16) float xs[G1NODES*XPAD];   // 17.4 KB
    bool w64 = ei_is_i64(ei);
    int t = threadIdx.x;
    int gb = swz1024((int)blockIdx.x);   // graph g -> residue g>>4
    int b  = gb >> 3;                    // graph
    int sub = gb & 7;
    int node0 = b*NN + sub*G1NODES;

    // ---- build: issue edge loads NOW (fire-and-forget; consumed later) ----
    int e = b*EDGPG + sub*512 + t;
    int dv = (ld_dst(ei, e, w64) - b*NN) & (NN - 1);   // local dst
    int sv = ld_src(ei, e, w64) & (NN - 1);            // LOCAL src id
    int anode = b*NN + dv;
    int p = ROWCAP;

    int tc = t & 15, tr = t >> 4;       // 16 col-groups x 32 row-groups
    int j0 = tc*4, n0 = tr*2;
    float acc[2][4] = {};

    // ---- stage half-0 to LDS ----
    {
        const float4* Wv0 = (const float4*)W1;
        for (int i = t; i < 1024; i += 512)
            *(float4*)&Ws[i*4] = Wv0[i];
        for (int i = t; i < 1024; i += 512){
            int node = i >> 4, c = i & 15;
            *(float4*)&xs[node*XPAD + c*4] =
                *(const float4*)(x + (size_t)(node0 + node)*F_IN + c*4);
        }
    }
    __syncthreads();
    p = atomicAdd(&cnt[anode], 1);      // single-XCD contention now
    // ---- prefetch half-1 into regs (fly under half-0 FMAs) ----
    const float4* Wv1 = (const float4*)(W1 + 4096);
    float4 wr0 = Wv1[t], wr1 = Wv1[t + 512];
    float4 xr0 = *(const float4*)(x + (size_t)(node0 + (t >> 4))*F_IN + 64 + (t & 15)*4);
    float4 xr1 = *(const float4*)(x + (size_t)(node0 + ((t+512) >> 4))*F_IN + 64 + ((t+512) & 15)*4);

    // ---- FMA half-0 ----
    #pragma unroll 2
    for (int k = 0; k < 64; k += 4){
        float4 xv0 = *(const float4*)&xs[(n0+0)*XPAD + k];
        float4 xv1 = *(const float4*)&xs[(n0+1)*XPAD + k];
        float xa0[4] = {xv0.x, xv0.y, xv0.z, xv0.w};
        float xa1[4] = {xv1.x, xv1.y, xv1.z, xv1.w};
        #pragma unroll
        for (int kk = 0; kk < 4; ++kk){
            float4 wv = *(const float4*)&Ws[(k+kk)*H1 + j0];
            acc[0][0] += xa0[kk]*wv.x; acc[0][1] += xa0[kk]*wv.y; acc[0][2] += xa0[kk]*wv.z; acc[0][3] += xa0[kk]*wv.w;
            acc[1][0] += xa1[kk]*wv.x; acc[1][1] += xa1[kk]*wv.y; acc[1][2] += xa1[kk]*wv.z; acc[1][3] += xa1[kk]*wv.w;
        }
    }
    __syncthreads();
    // ---- write half-1 from regs (same LDS addresses as old staging) ----
    *(float4*)&Ws[(t      )*4] = wr0;
    *(float4*)&Ws[(t + 512)*4] = wr1;
    *(float4*)&xs[((t      ) >> 4)*XPAD + ((t      ) & 15)*4] = xr0;
    *(float4*)&xs[((t + 512) >> 4)*XPAD + ((t + 512) & 15)*4] = xr1;
    __syncthreads();
    // ---- FMA half-1 ----
    #pragma unroll 2
    for (int k = 0; k < 64; k += 4){
        float4 xv0 = *(const float4*)&xs[(n0+0)*XPAD + k];
        float4 xv1 = *(const float4*)&xs[(n0+1)*XPAD + k];
        float xa0[4] = {xv0.x, xv0.y, xv0.z, xv0.w};
        float xa1[4] = {xv1.x, xv1.y, xv1.z, xv1.w};
        #pragma unroll
        for (int kk = 0; kk < 4; ++kk){
            float4 wv = *(const float4*)&Ws[(k+kk)*H1 + j0];
            acc[0][0] += xa0[kk]*wv.x; acc[0][1] += xa0[kk]*wv.y; acc[0][2] += xa0[kk]*wv.z; acc[0][3] += xa0[kk]*wv.w;
            acc[1][0] += xa1[kk]*wv.x; acc[1][1] += xa1[kk]*wv.y; acc[1][2] += xa1[kk]*wv.z; acc[1][3] += xa1[kk]*wv.w;
        }
    }
    // ---- deferred build stores (u16 local ids) ----
    if (p < ROWCAP - 1) adj[(size_t)anode*ROWCAP + 1 + p] = (u16)sv;
    if (t < G1NODES){
        int node = node0 + t;
        adj[(size_t)node*ROWCAP] = (u16)(node & (NN - 1));   // self loop
    }
    #pragma unroll
    for (int i = 0; i < 2; ++i){
        int node = node0 + n0 + i;
        size_t base = (size_t)node*32 + tc*2;
        h1u[base]     = packbf(acc[i][0], acc[i][1]);
        h1u[base + 1] = packbf(acc[i][2], acc[i][3]);
    }
}

// ---- K2: a1' = dis*relu(dis*sum dis[s]*h1[s] + b1), 16-entry prefetch ----
__global__ __launch_bounds__(256) void k_agg1(const uint4* __restrict__ h1v,
                                              const int* __restrict__ cnt,
                                              const u16* __restrict__ adj,
                                              const float4* __restrict__ b1v,
                                              uint4* __restrict__ a1v){
    __shared__ float disl[NN];     // per-graph dis table (2 KB)
    int t = threadIdx.x;
    int lb = swz2048((int)blockIdx.x);
    int node0 = lb*32;
    int gbase = node0 & ~(NN - 1);
    int node = node0 + (t >> 3);
    int nl = node & (NN - 1);
    int fl = t & 7;
    size_t rs = (size_t)node*ROWCAP;
    // ---- entry prefetch: in flight during disl build + barrier ----
    int cp = cnt[node];
    uint4 apA = *(const uint4*)&adj[rs];       // entries 0..7 (0 = self)
    uint4 apB = *(const uint4*)&adj[rs + 8];   // entries 8..15
    uint4 vself = h1v[(size_t)node*8 + fl];
    for (int i = t; i < NN; i += 256){
        int c = cnt[gbase + i]; if (c > ROWCAP-1) c = ROWCAP-1;
        disl[i] = rsqrtf((float)(c + 1));
    }
    __syncthreads();
    int c = cp; if (c > ROWCAP-1) c = ROWCAP-1;
    int ne = c + 1;
    int e1 = (int)(apA.x >> 16);
    int e2 = (int)(apA.y & 0xffff), e3 = (int)(apA.y >> 16);
    int e4 = (int)(apA.z & 0xffff), e5 = (int)(apA.z >> 16);
    int e6 = (int)(apA.w & 0xffff), e7 = (int)(apA.w >> 16);
    int e8  = (int)(apB.x & 0xffff), e9  = (int)(apB.x >> 16);
    int e10 = (int)(apB.y & 0xffff), e11 = (int)(apB.y >> 16);
    int e12 = (int)(apB.z & 0xffff), e13 = (int)(apB.z >> 16);
    int e14 = (int)(apB.w & 0xffff), e15 = (int)(apB.w >> 16);
    float a0[8] = {}, a1r[8] = {}, a2r[8] = {}, a3r[8] = {};
    int p = 0;
    if (p + 4 <= ne){        // quad 0 (entry 0 = self)
        float d0 = disl[nl], d1 = disl[e1], d2 = disl[e2], d3 = disl[e3];
        uint4 v1 = h1v[(size_t)(gbase + e1)*8 + fl];
        uint4 v2 = h1v[(size_t)(gbase + e2)*8 + fl];
        uint4 v3 = h1v[(size_t)(gbase + e3)*8 + fl];
        acc8s(a0, vself, d0); acc8s(a1r, v1, d1); acc8s(a2r, v2, d2); acc8s(a3r, v3, d3);
        p += 4;
    }
    if (p + 4 <= ne){        // quad 1
        float d0 = disl[e4], d1 = disl[e5], d2 = disl[e6], d3 = disl[e7];
        uint4 v0 = h1v[(size_t)(gbase + e4)*8 + fl];
        uint4 v1 = h1v[(size_t)(gbase + e5)*8 + fl];
        uint4 v2 = h1v[(size_t)(gbase + e6)*8 + fl];
        uint4 v3 = h1v[(size_t)(gbase + e7)*8 + fl];
        acc8s(a0, v0, d0); acc8s(a1r, v1, d1); acc8s(a2r, v2, d2); acc8s(a3r, v3, d3);
        p += 4;
    }
    if (p + 4 <= ne){        // quad 2
        float d0 = disl[e8], d1 = disl[e9], d2 = disl[e10], d3 = disl[e11];
        uint4 v0 = h1v[(size_t)(gbase + e8 )*8 + fl];
        uint4 v1 = h1v[(size_t)(gbase + e9 )*8 + fl];
        uint4 v2 = h1v[(size_t)(gbase + e10)*8 + fl];
        uint4 v3 = h1v[(size_t)(gbase + e11)*8 + fl];
        acc8s(a0, v0, d0); acc8s(a1r, v1, d1); acc8s(a2r, v2, d2); acc8s(a3r, v3, d3);
        p += 4;
    }
    if (p + 4 <= ne){        // quad 3
        float d0 = disl[e12], d1 = disl[e13], d2 = disl[e14], d3 = disl[e15];
        uint4 v0 = h1v[(size_t)(gbase + e12)*8 + fl];
        uint4 v1 = h1v[(size_t)(gbase + e13)*8 + fl];
        uint4 v2 = h1v[(size_t)(gbase + e14)*8 + fl];
        uint4 v3 = h1v[(size_t)(gbase + e15)*8 + fl];
        acc8s(a0, v0, d0); acc8s(a1r, v1, d1); acc8s(a2r, v2, d2); acc8s(a3r, v3, d3);
        p += 4;
    }
    for (; p + 4 <= ne; p += 4){    // rare: deg > 15
        int s0 = adj[rs+p], s1 = adj[rs+p+1], s2 = adj[rs+p+2], s3 = adj[rs+p+3];
        float d0 = disl[s0], d1 = disl[s1], d2 = disl[s2], d3 = disl[s3];
        uint4 v0 = h1v[(size_t)(gbase + s0)*8 + fl];
        uint4 v1 = h1v[(size_t)(gbase + s1)*8 + fl];
        uint4 v2 = h1v[(size_t)(gbase + s2)*8 + fl];
        uint4 v3 = h1v[(size_t)(gbase + s3)*8 + fl];
        acc8s(a0, v0, d0); acc8s(a1r, v1, d1); acc8s(a2r, v2, d2); acc8s(a3r, v3, d3);
    }
    for (; p < ne; ++p){            // tail singles (line already in L1)
        int s = adj[rs + p];
        acc8s(a0, h1v[(size_t)(gbase + s)*8 + fl], disl[s]);
    }
    float r[8];
    #pragma unroll
    for (int j = 0; j < 8; ++j) r[j] = (a0[j] + a1r[j]) + (a2r[j] + a3r[j]);
    float dn = disl[nl];
    float4 bA = b1v[2*fl], bB = b1v[2*fl+1];
    float w0 = dn*r[0] + bA.x; w0 = w0 > 0.f ? w0 : 0.f;
    float w1 = dn*r[1] + bA.y; w1 = w1 > 0.f ? w1 : 0.f;
    float w2 = dn*r[2] + bA.z; w2 = w2 > 0.f ? w2 : 0.f;
    float w3 = dn*r[3] + bA.w; w3 = w3 > 0.f ? w3 : 0.f;
    float w4 = dn*r[4] + bB.x; w4 = w4 > 0.f ? w4 : 0.f;
    float w5 = dn*r[5] + bB.y; w5 = w5 > 0.f ? w5 : 0.f;
    float w6 = dn*r[6] + bB.z; w6 = w6 > 0.f ? w6 : 0.f;
    float w7 = dn*r[7] + bB.w; w7 = w7 > 0.f ? w7 : 0.f;
    a1v[node*8 + fl] = make_uint4(packbf(dn*w0, dn*w1), packbf(dn*w2, dn*w3),
                                  packbf(dn*w4, dn*w5), packbf(dn*w6, dn*w7));
}

// ---- K3: fused aggpre + gemm2 + score, full interleave + u16 adj ----
#define G2NODES 32
#define APAD 68
__global__ __launch_bounds__(256) void k_gemm2s(const uint4* __restrict__ a1v,
                                                const int* __restrict__ cnt,
                                                const u16* __restrict__ adj,
                                                const float* __restrict__ W2,
                                                const float* __restrict__ b2,
                                                const float* __restrict__ pw,
                                                u32* __restrict__ a2u,
                                                float* __restrict__ score){
    __shared__ __align__(16) float Ws[32*H2];          // 16 KB (one k-half)
    __shared__ __align__(16) float as[G2NODES*APAD];   // 8.7 KB (full k, f32)
    __shared__ float pws[H2];
    int t = threadIdx.x;
    int lb = swz2048((int)blockIdx.x);
    int node0 = lb*G2NODES;
    int gbase = node0 & ~(NN - 1);
    int fl = t & 7, nl = t >> 3;
    int nodeg = node0 + nl;
    size_t rsg = (size_t)nodeg*ROWCAP;
    // ---- entry prefetch: gather-chain heads first, then W2 half-0 ----
    int cp = cnt[nodeg];
    uint4 apA = *(const uint4*)&adj[rsg];
    uint4 apB = *(const uint4*)&adj[rsg + 8];
    uint4 vself = a1v[(size_t)nodeg*8 + fl];
    const float4* Wv0 = (const float4*)W2;
    float4 w0a = Wv0[t], w0b = Wv0[t+256], w0c = Wv0[t+512], w0d = Wv0[t+768];
    if (t < H2) pws[t] = pw[t];
    // ---- fused aggpre: 8 lanes/node, all 32 nodes in one pass ----
    {
        int c = cp; if (c > ROWCAP-1) c = ROWCAP-1;
        int ne = c + 1;
        int e1 = (int)(apA.x >> 16);
        int e2 = (int)(apA.y & 0xffff), e3 = (int)(apA.y >> 16);
        int e4 = (int)(apA.z & 0xffff), e5 = (int)(apA.z >> 16);
        int e6 = (int)(apA.w & 0xffff), e7 = (int)(apA.w >> 16);
        int e8  = (int)(apB.x & 0xffff), e9  = (int)(apB.x >> 16);
        int e10 = (int)(apB.y & 0xffff), e11 = (int)(apB.y >> 16);
        int e12 = (int)(apB.z & 0xffff), e13 = (int)(apB.z >> 16);
        int e14 = (int)(apB.w & 0xffff), e15 = (int)(apB.w >> 16);
        float a0[8] = {}, a1r[8] = {}, a2r[8] = {}, a3r[8] = {};
        int p = 0;
        if (p + 4 <= ne){       // quad 0 (entry 0 = self)
            uint4 v1 = a1v[(size_t)(gbase + e1)*8 + fl];
            uint4 v2 = a1v[(size_t)(gbase + e2)*8 + fl];
            uint4 v3 = a1v[(size_t)(gbase + e3)*8 + fl];
            acc8(a0, vself); acc8(a1r, v1); acc8(a2r, v2); acc8(a3r, v3);
            p += 4;
        }
        if (p + 4 <= ne){       // quad 1
            uint4 v0 = a1v[(size_t)(gbase + e4)*8 + fl];
            uint4 v1 = a1v[(size_t)(gbase + e5)*8 + fl];
            uint4 v2 = a1v[(size_t)(gbase + e6)*8 + fl];
            uint4 v3 = a1v[(size_t)(gbase + e7)*8 + fl];
            acc8(a0, v0); acc8(a1r, v1); acc8(a2r, v2); acc8(a3r, v3);
            p += 4;
        }
        if (p + 4 <= ne){       // quad 2
            uint4 v0 = a1v[(size_t)(gbase + e8 )*8 + fl];
            uint4 v1 = a1v[(size_t)(gbase + e9 )*8 + fl];
            uint4 v2 = a1v[(size_t)(gbase + e10)*8 + fl];
            uint4 v3 = a1v[(size_t)(gbase + e11)*8 + fl];
            acc8(a0, v0); acc8(a1r, v1); acc8(a2r, v2); acc8(a3r, v3);
            p += 4;
        }
        if (p + 4 <= ne){       // quad 3
            uint4 v0 = a1v[(size_t)(gbase + e12)*8 + fl];
            uint4 v1 = a1v[(size_t)(gbase + e13)*8 + fl];
            uint4 v2 = a1v[(size_t)(gbase + e14)*8 + fl];
            uint4 v3 = a1v[(size_t)(gbase + e15)*8 + fl];
            acc8(a0, v0); acc8(a1r, v1); acc8(a2r, v2); acc8(a3r, v3);
            p += 4;
        }
        for (; p + 4 <= ne; p += 4){    // rare: deg > 15
            int s0 = adj[rsg+p], s1 = adj[rsg+p+1], s2 = adj[rsg+p+2], s3 = adj[rsg+p+3];
            uint4 v0 = a1v[(size_t)(gbase + s0)*8 + fl];
            uint4 v1 = a1v[(size_t)(gbase + s1)*8 + fl];
            uint4 v2 = a1v[(size_t)(gbase + s2)*8 + fl];
            uint4 v3 = a1v[(size_t)(gbase + s3)*8 + fl];
            acc8(a0, v0); acc8(a1r, v1); acc8(a2r, v2); acc8(a3r, v3);
        }
        for (; p < ne; ++p){
            int s = adj[rsg + p];
            acc8(a0, a1v[(size_t)(gbase + s)*8 + fl]);
        }
        float dn = rsqrtf((float)(c + 1));
        float* dst = &as[nl*APAD + 8*fl];
        float r0 = dn*((a0[0] + a1r[0]) + (a2r[0] + a3r[0]));
        float r1 = dn*((a0[1] + a1r[1]) + (a2r[1] + a3r[1]));
        float r2 = dn*((a0[2] + a1r[2]) + (a2r[2] + a3r[2]));
        float r3 = dn*((a0[3] + a1r[3]) + (a2r[3] + a3r[3]));
        float r4 = dn*((a0[4] + a1r[4]) + (a2r[4] + a3r[4]));
        float r5 = dn*((a0[5] + a1r[5]) + (a2r[5] + a3r[5]));
        float r6 = dn*((a0[6] + a1r[6]) + (a2r[6] + a3r[6]));
        float r7 = dn*((a0[7] + a1r[7]) + (a2r[7] + a3r[7]));
        *(float4*)&dst[0] = make_float4(r0, r1, r2, r3);
        *(float4*)&dst[4] = make_float4(r4, r5, r6, r7);
    }
    // ---- write half-0 Ws from regs ----
    *(float4*)&Ws[(t      )*4] = w0a;
    *(float4*)&Ws[(t + 256)*4] = w0b;
    *(float4*)&Ws[(t + 512)*4] = w0c;
    *(float4*)&Ws[(t + 768)*4] = w0d;
    __syncthreads();                       // covers as + pws + Ws half-0
    // ---- issue W2 half-1 loads (fly under FMA half-0) ----
    const float4* Wv1 = (const float4*)(W2 + 4096);
    float4 w1a = Wv1[t], w1b = Wv1[t+256], w1c = Wv1[t+512], w1d = Wv1[t+768];

    int tc = t & 31, tr = t >> 5;
    int j0 = tc*4, n0 = tr*4;
    float acc[4][4] = {};
    #pragma unroll
    for (int half = 0; half < 2; ++half){
        int kb = half*32;
        #pragma unroll 2
        for (int k = 0; k < 32; k += 4){
            float4 xv0 = *(const float4*)&as[(n0+0)*APAD + kb + k];
            float4 xv1 = *(const float4*)&as[(n0+1)*APAD + kb + k];
            float4 xv2 = *(const float4*)&as[(n0+2)*APAD + kb + k];
            float4 xv3 = *(const float4*)&as[(n0+3)*APAD + kb + k];
            float xa0[4] = {xv0.x, xv0.y, xv0.z, xv0.w};
            float xa1[4] = {xv1.x, xv1.y, xv1.z, xv1.w};
            float xa2[4] = {xv2.x, xv2.y, xv2.z, xv2.w};
            float xa3[4] = {xv3.x, xv3.y, xv3.z, xv3.w};
            #pragma unroll
            for (int kk = 0; kk < 4; ++kk){
                float4 wv = *(const float4*)&Ws[(k+kk)*H2 + j0];
                acc[0][0] += xa0[kk]*wv.x; acc[0][1] += xa0[kk]*wv.y; acc[0][2] += xa0[kk]*wv.z; acc[0][3] += xa0[kk]*wv.w;
                acc[1][0] += xa1[kk]*wv.x; acc[1][1] += xa1[kk]*wv.y; acc[1][2] += xa1[kk]*wv.z; acc[1][3] += xa1[kk]*wv.w;
                acc[2][0] += xa2[kk]*wv.x; acc[2][1] += xa2[kk]*wv.y; acc[2][2] += xa2[kk]*wv.z; acc[2][3] += xa2[kk]*wv.w;
                acc[3][0] += xa3[kk]*wv.x; acc[3][1] += xa3[kk]*wv.y; acc[3][2] += xa3[kk]*wv.z; acc[3][3] += xa3[kk]*wv.w;
            }
        }
        if (half == 0){
            __syncthreads();               // all done reading Ws half-0
            *(float4*)&Ws[(t      )*4] = w1a;
            *(float4*)&Ws[(t + 256)*4] = w1b;
            *(float4*)&Ws[(t + 512)*4] = w1c;
            *(float4*)&Ws[(t + 768)*4] = w1d;
            __syncthreads();               // Ws half-1 visible
        }
    }
    float p0 = pws[j0], p1 = pws[j0+1], p2 = pws[j0+2], p3 = pws[j0+3];
    float bj0 = b2[j0], bj1 = b2[j0+1], bj2 = b2[j0+2], bj3 = b2[j0+3];
    #pragma unroll
    for (int i = 0; i < 4; ++i){
        float v0 = acc[i][0] + bj0; v0 = v0 > 0.f ? v0 : 0.f;
        float v1 = acc[i][1] + bj1; v1 = v1 > 0.f ? v1 : 0.f;
        float v2 = acc[i][2] + bj2; v2 = v2 > 0.f ? v2 : 0.f;
        float v3 = acc[i][3] + bj3; v3 = v3 > 0.f ? v3 : 0.f;
        size_t base = (size_t)(node0 + n0 + i)*64 + tc*2;
        a2u[base]     = packbf(v0, v1);
        a2u[base + 1] = packbf(v2, v3);
        float sp = v0*p0 + v1*p1 + v2*p2 + v3*p3;
        sp += __shfl_xor(sp, 16, 32);
        sp += __shfl_xor(sp,  8, 32);
        sp += __shfl_xor(sp,  4, 32);
        sp += __shfl_xor(sp,  2, 32);
        sp += __shfl_xor(sp,  1, 32);
        if (tc == 0) score[node0 + n0 + i] = sp;   // raw (unscaled) dot
    }
}

// ---- K4: per-graph top-K pool + FC + log_softmax (shfl-bitonic, r29) ----
__global__ __launch_bounds__(512) void k_pool(const u32* __restrict__ a2u,
                                              const float* __restrict__ score,
                                              const float* __restrict__ pw,
                                              const float* __restrict__ fcW,
                                              const float* __restrict__ fcb,
                                              float* __restrict__ out){
    __shared__ float so[NN];
    __shared__ float ss[NN];
    __shared__ float th[NN];
    __shared__ float pm[32*H2];    // 16 KB
    __shared__ float gl[H2];
    __shared__ float fws[H2*NC];   // 5 KB
    __shared__ float lg[NC];
    __shared__ float red[3];
    int bid = blockIdx.x, t = threadIdx.x;
    int b = ((bid & 7) << 4) | (bid >> 3);     // match gemm2s graph->XCD residue
    float sc = score[b*NN + t];                // prefetch at entry
    for (int i = t; i < H2*NC; i += 512) fws[i] = fcW[i];
    if (t < H2){ float v2 = pw[t]; gl[t] = v2*v2; }
    __syncthreads();
    if (t == 0){
        float s = 0.f;
        for (int i = 0; i < H2; ++i) s += gl[i];
        red[2] = rsqrtf(s);
    }
    __syncthreads();
    float pwinv = red[2];
    so[t] = sc; th[t] = tanhf(sc*pwinv);
    // bitonic sort descending, value in register v (j<64 via shfl)
    float v = sc;
    for (int k = 2; k <= NN; k <<= 1){
        for (int j = k >> 1; j > 0; j >>= 1){
            bool desc  = ((t & k) == 0);
            bool lower = ((t & j) == 0);
            bool wantmax = (desc == lower);
            float c;
            if (j >= 64){
                ss[t] = v; __syncthreads();
                c = ss[t ^ j];
                __syncthreads();
            } else {
                c = __shfl_xor(v, j, 64);
            }
            v = wantmax ? fmaxf(v, c) : fminf(v, c);
        }
    }
    ss[t] = v;
    __syncthreads();
    float thresh = ss[KSEL-1];
    float mask_t = (so[t] >= thresh) ? 0.f : -INFINITY;
    __syncthreads();
    so[t] = mask_t;
    __syncthreads();
    // gated max: lane tc handles feats {8tc..8tc+7} via uint4; group q: 16 nodes
    int tc = t & 15, q = t >> 4;
    const uint4* ap = (const uint4*)(a2u + (size_t)b*NN*64);
    float m0 = -INFINITY, m1 = -INFINITY, m2 = -INFINITY, m3 = -INFINITY;
    float m4 = -INFINITY, m5 = -INFINITY, m6 = -INFINITY, m7 = -INFINITY;
    int nb = q*16;
    #pragma unroll 4
    for (int n = nb; n < nb + 16; ++n){
        uint4 vv = ap[(size_t)n*16 + tc];
        float thn = th[n], son = so[n];
        m0 = fmaxf(m0, lo2f(vv.x)*thn + son);
        m1 = fmaxf(m1, hi2f(vv.x)*thn + son);
        m2 = fmaxf(m2, lo2f(vv.y)*thn + son);
        m3 = fmaxf(m3, hi2f(vv.y)*thn + son);
        m4 = fmaxf(m4, lo2f(vv.z)*thn + son);
        m5 = fmaxf(m5, hi2f(vv.z)*thn + son);
        m6 = fmaxf(m6, lo2f(vv.w)*thn + son);
        m7 = fmaxf(m7, hi2f(vv.w)*thn + son);
    }
    float* pmr = &pm[q*H2 + 8*tc];
    pmr[0] = m0; pmr[1] = m1; pmr[2] = m2; pmr[3] = m3;
    pmr[4] = m4; pmr[5] = m5; pmr[6] = m6; pmr[7] = m7;
    __syncthreads();
    if (t < H2){
        float g = pm[t];
        #pragma unroll
        for (int qq = 1; qq < 32; ++qq) g = fmaxf(g, pm[qq*H2 + t]);
        gl[t] = g;
    }
    __syncthreads();
    if (t < NC){
        float acc = fcb[t];
        for (int k2 = 0; k2 < H2; ++k2) acc += gl[k2]*fws[k2*NC + t];
        lg[t] = acc;
    }
    __syncthreads();
    if (t == 0){
        float mx = lg[0];
        for (int i = 1; i < NC; ++i) mx = fmaxf(mx, lg[i]);
        float s = 0.f;
        for (int i = 0; i < NC; ++i) s += expf(lg[i] - mx);
        red[0] = mx; red[1] = logf(s);
    }
    __syncthreads();
    if (t < NC) out[b*NC + t] = lg[t] - red[0] - red[1];
}

extern "C" void kernel_launch(void* const* d_in, const int* in_sizes, int n_in,
                              void* d_out, int out_size, void* d_ws, size_t ws_size,
                              hipStream_t stream) {
    const float* x   = (const float*)d_in[0];
    const int*   ei  = (const int*)d_in[1];
    // d_in[2] = batch (unused; batch = node / NN)
    const float* W1  = (const float*)d_in[3];
    const float* b1  = (const float*)d_in[4];
    const float* W2  = (const float*)d_in[5];
    const float* b2  = (const float*)d_in[6];
    const float* pw  = (const float*)d_in[7];
    const float* fcW = (const float*)d_in[8];
    const float* fcb = (const float*)d_in[9];

    char* ws = (char*)d_ws;
    int*   cnt   = (int*)(ws + 4096);            // 256 KB
    float* score = (float*)(ws + 524288);        // 256 KB
    u16*   adj   = (u16*)(ws + 4194304);         // NODES*48*2 = 6.3 MB
    u32*   h1u   = (u32*)(ws + 16777216);        // 8 MB
    u32*   a1u   = (u32*)(ws + 25165824);        // 8 MB
    u32*   a2u   = (u32*)(ws + 33554432);        // 16 MB

    hipMemsetAsync(cnt, 0, NODES*sizeof(int), stream);
    k_prep_gemm1<<<NODES/G1NODES, 512, 0, stream>>>(ei, x, W1, cnt, adj, h1u);
    k_agg1<<<NODES/32, 256, 0, stream>>>((const uint4*)h1u, cnt, adj,
                                         (const float4*)b1, (uint4*)a1u);
    k_gemm2s<<<NODES/G2NODES, 256, 0, stream>>>((const uint4*)a1u, cnt, adj,
                                                W2, b2, pw, a2u, score);
    k_pool<<<BB, 512, 0, stream>>>(a2u, score, pw, fcW, fcb, (float*)d_out);
}

// Round 13
// 163.201 us; speedup vs baseline: 1.1194x; 1.1194x over previous
//
#include <hip/hip_runtime.h>
#include <hip/hip_bf16.h>

// Float inputs/outputs FP32; intermediates packed-bf16 (uint4).
// r27 (169.4): build-interleave in prep. r28 (165.7): W2 reg-double-buffer
// in gemm2s. r29 (163.4, CHAMPION): interleave everywhere (prep half-1 regs,
// gather-head entry prefetch, pool score hoist).
// r30 FAILED (182.7): u16 adj scattered sub-dword stores + prep swizzle blew
// prep up to 53-59us (WRITE dropped 33->22MB but store path slower).
// r31 (this round): EXACT revert to r29. If this confirms ~163us, the
// pipeline is at its structural floor (43us uncontrollable re-poison fill +
// latency-floored kernels + dispatch overhead) -> ROOFLINE.

#define BB 128
#define NN 512
#define NODES (BB*NN)          // 65536
#define EE (BB*NN*8)           // 524288
#define EDGPG (NN*8)           // 4096 edges per graph
#define F_IN 128
#define H1 64
#define H2 128
#define NC 10
#define KSEL 410
#define ROWCAP 48              // 1 self + up to 47 edges; P(indeg>=47) ~ 1e-22

typedef unsigned short u16;
typedef unsigned int   u32;

static __device__ __forceinline__ float lo2f(u32 u){ return __uint_as_float(u << 16); }
static __device__ __forceinline__ float hi2f(u32 u){ return __uint_as_float(u & 0xffff0000u); }
static __device__ __forceinline__ u16 f2b(float f){
    __hip_bfloat16 h = __float2bfloat16(f);   // RNE
    return *reinterpret_cast<u16*>(&h);
}
static __device__ __forceinline__ u32 packbf(float a, float b){
    return (u32)f2b(a) | ((u32)f2b(b) << 16);
}
static __device__ __forceinline__ void acc8s(float* a, uint4 v, float ds){
    a[0] = fmaf(ds, lo2f(v.x), a[0]); a[1] = fmaf(ds, hi2f(v.x), a[1]);
    a[2] = fmaf(ds, lo2f(v.y), a[2]); a[3] = fmaf(ds, hi2f(v.y), a[3]);
    a[4] = fmaf(ds, lo2f(v.z), a[4]); a[5] = fmaf(ds, hi2f(v.z), a[5]);
    a[6] = fmaf(ds, lo2f(v.w), a[6]); a[7] = fmaf(ds, hi2f(v.w), a[7]);
}
static __device__ __forceinline__ void acc8(float* a, uint4 v){
    a[0] += lo2f(v.x); a[1] += hi2f(v.x);
    a[2] += lo2f(v.y); a[3] += hi2f(v.y);
    a[4] += lo2f(v.z); a[5] += hi2f(v.z);
    a[6] += lo2f(v.w); a[7] += hi2f(v.w);
}
// XCD swizzle: all 16 blocks of one graph -> same residue mod 8 -> same XCD.
static __device__ __forceinline__ int swz2048(int bid){
    return ((bid & 7) << 8) | (bid >> 3);
}

// edge_index may arrive as int64 (odd 32-bit words all zero) or int32.
static __device__ __forceinline__ bool ei_is_i64(const int* __restrict__ ei){
    return ((ei[1] | ei[3] | ei[5] | ei[7]) == 0);
}
static __device__ __forceinline__ int ld_src(const int* __restrict__ ei, int e, bool w64){
    return w64 ? ei[2*e] : ei[e];
}
static __device__ __forceinline__ int ld_dst(const int* __restrict__ ei, int e, bool w64){
    return w64 ? ei[2*(EE + e)] : ei[EE + e];
}

// ---- K1: build (INTERLEAVED) + gemm1, half-1 reg-double-buffered ----
#define G1NODES 64
#define XPAD 68
__global__ __launch_bounds__(512) void k_prep_gemm1(const int* __restrict__ ei,
                                                    const float* __restrict__ x,
                                                    const float* __restrict__ W1,
                                                    int* __restrict__ cnt,
                                                    int* __restrict__ adj,
                                                    u32* __restrict__ h1u){
    __shared__ __align__(16) float Ws[64*H1];          // 16 KB (one k-half)
    __shared__ __align__(16) float xs[G1NODES*XPAD];   // 17.4 KB
    bool w64 = ei_is_i64(ei);
    int t = threadIdx.x;
    int gb = (int)blockIdx.x;        // 0..1023
    int b  = gb >> 3;                // graph
    int sub = gb & 7;
    int node0 = b*NN + sub*G1NODES;

    // ---- build: issue edge loads NOW (fire-and-forget; consumed later) ----
    int e = b*EDGPG + sub*512 + t;
    int dv = (ld_dst(ei, e, w64) - b*NN) & (NN - 1);   // local dst
    int sv = ld_src(ei, e, w64) & (NODES - 1);         // global src
    int anode = b*NN + dv;
    int p = ROWCAP;

    int tc = t & 15, tr = t >> 4;       // 16 col-groups x 32 row-groups
    int j0 = tc*4, n0 = tr*2;
    float acc[2][4] = {};

    // ---- stage half-0 to LDS ----
    {
        const float4* Wv0 = (const float4*)W1;
        for (int i = t; i < 1024; i += 512)
            *(float4*)&Ws[i*4] = Wv0[i];
        for (int i = t; i < 1024; i += 512){
            int node = i >> 4, c = i & 15;
            *(float4*)&xs[node*XPAD + c*4] =
                *(const float4*)(x + (size_t)(node0 + node)*F_IN + c*4);
        }
    }
    __syncthreads();
    p = atomicAdd(&cnt[anode], 1);      // contention resolves under FMAs
    // ---- prefetch half-1 into regs (fly under half-0 FMAs) ----
    const float4* Wv1 = (const float4*)(W1 + 4096);
    float4 wr0 = Wv1[t], wr1 = Wv1[t + 512];
    float4 xr0 = *(const float4*)(x + (size_t)(node0 + (t >> 4))*F_IN + 64 + (t & 15)*4);
    float4 xr1 = *(const float4*)(x + (size_t)(node0 + ((t+512) >> 4))*F_IN + 64 + ((t+512) & 15)*4);

    // ---- FMA half-0 ----
    #pragma unroll 2
    for (int k = 0; k < 64; k += 4){
        float4 xv0 = *(const float4*)&xs[(n0+0)*XPAD + k];
        float4 xv1 = *(const float4*)&xs[(n0+1)*XPAD + k];
        float xa0[4] = {xv0.x, xv0.y, xv0.z, xv0.w};
        float xa1[4] = {xv1.x, xv1.y, xv1.z, xv1.w};
        #pragma unroll
        for (int kk = 0; kk < 4; ++kk){
            float4 wv = *(const float4*)&Ws[(k+kk)*H1 + j0];
            acc[0][0] += xa0[kk]*wv.x; acc[0][1] += xa0[kk]*wv.y; acc[0][2] += xa0[kk]*wv.z; acc[0][3] += xa0[kk]*wv.w;
            acc[1][0] += xa1[kk]*wv.x; acc[1][1] += xa1[kk]*wv.y; acc[1][2] += xa1[kk]*wv.z; acc[1][3] += xa1[kk]*wv.w;
        }
    }
    __syncthreads();
    // ---- write half-1 from regs (same LDS addresses as old staging) ----
    *(float4*)&Ws[(t      )*4] = wr0;
    *(float4*)&Ws[(t + 512)*4] = wr1;
    *(float4*)&xs[((t      ) >> 4)*XPAD + ((t      ) & 15)*4] = xr0;
    *(float4*)&xs[((t + 512) >> 4)*XPAD + ((t + 512) & 15)*4] = xr1;
    __syncthreads();
    // ---- FMA half-1 ----
    #pragma unroll 2
    for (int k = 0; k < 64; k += 4){
        float4 xv0 = *(const float4*)&xs[(n0+0)*XPAD + k];
        float4 xv1 = *(const float4*)&xs[(n0+1)*XPAD + k];
        float xa0[4] = {xv0.x, xv0.y, xv0.z, xv0.w};
        float xa1[4] = {xv1.x, xv1.y, xv1.z, xv1.w};
        #pragma unroll
        for (int kk = 0; kk < 4; ++kk){
            float4 wv = *(const float4*)&Ws[(k+kk)*H1 + j0];
            acc[0][0] += xa0[kk]*wv.x; acc[0][1] += xa0[kk]*wv.y; acc[0][2] += xa0[kk]*wv.z; acc[0][3] += xa0[kk]*wv.w;
            acc[1][0] += xa1[kk]*wv.x; acc[1][1] += xa1[kk]*wv.y; acc[1][2] += xa1[kk]*wv.z; acc[1][3] += xa1[kk]*wv.w;
        }
    }
    // ---- deferred build stores ----
    if (p < ROWCAP - 1) adj[anode*ROWCAP + 1 + p] = sv;   // slot 0 = self
    if (t < G1NODES){
        int node = node0 + t;
        adj[node*ROWCAP] = node;                          // self loop
    }
    #pragma unroll
    for (int i = 0; i < 2; ++i){
        int node = node0 + n0 + i;
        size_t base = (size_t)node*32 + tc*2;
        h1u[base]     = packbf(acc[i][0], acc[i][1]);
        h1u[base + 1] = packbf(acc[i][2], acc[i][3]);
    }
}

// ---- K2: a1' = dis*relu(dis*sum dis[s]*h1[s] + b1), entry-prefetched ----
__global__ __launch_bounds__(256) void k_agg1(const uint4* __restrict__ h1v,
                                              const int* __restrict__ cnt,
                                              const int* __restrict__ adj,
                                              const float4* __restrict__ b1v,
                                              uint4* __restrict__ a1v){
    __shared__ float disl[NN];     // per-graph dis table (2 KB)
    int t = threadIdx.x;
    int lb = swz2048((int)blockIdx.x);
    int node0 = lb*32;
    int node = node0 + (t >> 3);
    int fl = t & 7;
    int rs = node*ROWCAP;
    // ---- entry prefetch: in flight during disl build + barrier ----
    int cp = cnt[node];
    int4 ap0 = *(const int4*)&adj[rs];        // entries 0..3 (0 = self)
    int4 ap1 = *(const int4*)&adj[rs + 4];    // entries 4..7
    uint4 vself = h1v[(size_t)node*8 + fl];
    int gbase = node0 & ~(NN - 1);
    for (int i = t; i < NN; i += 256){
        int c = cnt[gbase + i]; if (c > ROWCAP-1) c = ROWCAP-1;
        disl[i] = rsqrtf((float)(c + 1));
    }
    __syncthreads();
    int c = cp; if (c > ROWCAP-1) c = ROWCAP-1;
    int pe = rs + c + 1;
    float a0[8] = {}, a1r[8] = {}, a2r[8] = {}, a3r[8] = {};
    int p = rs;
    if (p + 4 <= pe){        // quad 0 from prefetched regs (s0 == node)
        int s1 = ap0.y, s2 = ap0.z, s3 = ap0.w;
        float d0 = disl[node & (NN-1)];
        float d1 = disl[s1 & (NN-1)], d2 = disl[s2 & (NN-1)], d3 = disl[s3 & (NN-1)];
        uint4 v1 = h1v[s1*8 + fl];
        uint4 v2 = h1v[s2*8 + fl];
        uint4 v3 = h1v[s3*8 + fl];
        acc8s(a0, vself, d0); acc8s(a1r, v1, d1); acc8s(a2r, v2, d2); acc8s(a3r, v3, d3);
        p += 4;
    }
    if (p + 4 <= pe){        // quad 1 from prefetched adj regs
        int s0 = ap1.x, s1 = ap1.y, s2 = ap1.z, s3 = ap1.w;
        float d0 = disl[s0 & (NN-1)], d1 = disl[s1 & (NN-1)];
        float d2 = disl[s2 & (NN-1)], d3 = disl[s3 & (NN-1)];
        uint4 v0 = h1v[s0*8 + fl];
        uint4 v1 = h1v[s1*8 + fl];
        uint4 v2 = h1v[s2*8 + fl];
        uint4 v3 = h1v[s3*8 + fl];
        acc8s(a0, v0, d0); acc8s(a1r, v1, d1); acc8s(a2r, v2, d2); acc8s(a3r, v3, d3);
        p += 4;
    }
    for (; p + 4 <= pe; p += 4){
        int s0 = adj[p], s1 = adj[p+1], s2 = adj[p+2], s3 = adj[p+3];
        float d0 = disl[s0 & (NN-1)], d1 = disl[s1 & (NN-1)];
        float d2 = disl[s2 & (NN-1)], d3 = disl[s3 & (NN-1)];
        uint4 v0 = h1v[s0*8 + fl];
        uint4 v1 = h1v[s1*8 + fl];
        uint4 v2 = h1v[s2*8 + fl];
        uint4 v3 = h1v[s3*8 + fl];
        acc8s(a0, v0, d0); acc8s(a1r, v1, d1); acc8s(a2r, v2, d2); acc8s(a3r, v3, d3);
    }
    for (; p < pe; ++p){
        int s = adj[p];
        acc8s(a0, h1v[s*8 + fl], disl[s & (NN-1)]);
    }
    float r[8];
    #pragma unroll
    for (int j = 0; j < 8; ++j) r[j] = (a0[j] + a1r[j]) + (a2r[j] + a3r[j]);
    float dn = disl[node & (NN-1)];
    float4 bA = b1v[2*fl], bB = b1v[2*fl+1];
    float w0 = dn*r[0] + bA.x; w0 = w0 > 0.f ? w0 : 0.f;
    float w1 = dn*r[1] + bA.y; w1 = w1 > 0.f ? w1 : 0.f;
    float w2 = dn*r[2] + bA.z; w2 = w2 > 0.f ? w2 : 0.f;
    float w3 = dn*r[3] + bA.w; w3 = w3 > 0.f ? w3 : 0.f;
    float w4 = dn*r[4] + bB.x; w4 = w4 > 0.f ? w4 : 0.f;
    float w5 = dn*r[5] + bB.y; w5 = w5 > 0.f ? w5 : 0.f;
    float w6 = dn*r[6] + bB.z; w6 = w6 > 0.f ? w6 : 0.f;
    float w7 = dn*r[7] + bB.w; w7 = w7 > 0.f ? w7 : 0.f;
    a1v[node*8 + fl] = make_uint4(packbf(dn*w0, dn*w1), packbf(dn*w2, dn*w3),
                                  packbf(dn*w4, dn*w5), packbf(dn*w6, dn*w7));
}

// ---- K3: fused aggpre + gemm2 + score, full interleave ----
#define G2NODES 32
#define APAD 68
__global__ __launch_bounds__(256) void k_gemm2s(const uint4* __restrict__ a1v,
                                                const int* __restrict__ cnt,
                                                const int* __restrict__ adj,
                                                const float* __restrict__ W2,
                                                const float* __restrict__ b2,
                                                const float* __restrict__ pw,
                                                u32* __restrict__ a2u,
                                                float* __restrict__ score){
    __shared__ __align__(16) float Ws[32*H2];          // 16 KB (one k-half)
    __shared__ __align__(16) float as[G2NODES*APAD];   // 8.7 KB (full k, f32)
    __shared__ float pws[H2];
    int t = threadIdx.x;
    int lb = swz2048((int)blockIdx.x);
    int node0 = lb*G2NODES;
    int fl = t & 7, nl = t >> 3;
    int nodeg = node0 + nl;
    int rsg = nodeg*ROWCAP;
    // ---- entry prefetch: gather-chain heads first, then W2 half-0 ----
    int cp = cnt[nodeg];
    int4 ap0 = *(const int4*)&adj[rsg];
    int4 ap1 = *(const int4*)&adj[rsg + 4];
    uint4 vself = a1v[(size_t)nodeg*8 + fl];
    const float4* Wv0 = (const float4*)W2;
    float4 w0a = Wv0[t], w0b = Wv0[t+256], w0c = Wv0[t+512], w0d = Wv0[t+768];
    if (t < H2) pws[t] = pw[t];
    // ---- fused aggpre: 8 lanes/node, all 32 nodes in one pass ----
    {
        int c = cp; if (c > ROWCAP-1) c = ROWCAP-1;
        int pe = rsg + c + 1;
        float a0[8] = {}, a1r[8] = {}, a2r[8] = {}, a3r[8] = {};
        int p = rsg;
        if (p + 4 <= pe){       // quad 0: s0 == nodeg (self)
            int s1 = ap0.y, s2 = ap0.z, s3 = ap0.w;
            uint4 v1 = a1v[s1*8 + fl];
            uint4 v2 = a1v[s2*8 + fl];
            uint4 v3 = a1v[s3*8 + fl];
            acc8(a0, vself); acc8(a1r, v1); acc8(a2r, v2); acc8(a3r, v3);
            p += 4;
        }
        if (p + 4 <= pe){       // quad 1 from prefetched adj regs
            int s0 = ap1.x, s1 = ap1.y, s2 = ap1.z, s3 = ap1.w;
            uint4 v0 = a1v[s0*8 + fl];
            uint4 v1 = a1v[s1*8 + fl];
            uint4 v2 = a1v[s2*8 + fl];
            uint4 v3 = a1v[s3*8 + fl];
            acc8(a0, v0); acc8(a1r, v1); acc8(a2r, v2); acc8(a3r, v3);
            p += 4;
        }
        for (; p + 4 <= pe; p += 4){
            int s0 = adj[p], s1 = adj[p+1], s2 = adj[p+2], s3 = adj[p+3];
            uint4 v0 = a1v[s0*8 + fl];
            uint4 v1 = a1v[s1*8 + fl];
            uint4 v2 = a1v[s2*8 + fl];
            uint4 v3 = a1v[s3*8 + fl];
            acc8(a0, v0); acc8(a1r, v1); acc8(a2r, v2); acc8(a3r, v3);
        }
        for (; p < pe; ++p){
            uint4 v = a1v[adj[p]*8 + fl];
            acc8(a0, v);
        }
        float dn = rsqrtf((float)(c + 1));
        float* dst = &as[nl*APAD + 8*fl];
        float r0 = dn*((a0[0] + a1r[0]) + (a2r[0] + a3r[0]));
        float r1 = dn*((a0[1] + a1r[1]) + (a2r[1] + a3r[1]));
        float r2 = dn*((a0[2] + a1r[2]) + (a2r[2] + a3r[2]));
        float r3 = dn*((a0[3] + a1r[3]) + (a2r[3] + a3r[3]));
        float r4 = dn*((a0[4] + a1r[4]) + (a2r[4] + a3r[4]));
        float r5 = dn*((a0[5] + a1r[5]) + (a2r[5] + a3r[5]));
        float r6 = dn*((a0[6] + a1r[6]) + (a2r[6] + a3r[6]));
        float r7 = dn*((a0[7] + a1r[7]) + (a2r[7] + a3r[7]));
        *(float4*)&dst[0] = make_float4(r0, r1, r2, r3);
        *(float4*)&dst[4] = make_float4(r4, r5, r6, r7);
    }
    // ---- write half-0 Ws from regs ----
    *(float4*)&Ws[(t      )*4] = w0a;
    *(float4*)&Ws[(t + 256)*4] = w0b;
    *(float4*)&Ws[(t + 512)*4] = w0c;
    *(float4*)&Ws[(t + 768)*4] = w0d;
    __syncthreads();                       // covers as + pws + Ws half-0
    // ---- issue W2 half-1 loads (fly under FMA half-0) ----
    const float4* Wv1 = (const float4*)(W2 + 4096);
    float4 w1a = Wv1[t], w1b = Wv1[t+256], w1c = Wv1[t+512], w1d = Wv1[t+768];

    int tc = t & 31, tr = t >> 5;
    int j0 = tc*4, n0 = tr*4;
    float acc[4][4] = {};
    #pragma unroll
    for (int half = 0; half < 2; ++half){
        int kb = half*32;
        #pragma unroll 2
        for (int k = 0; k < 32; k += 4){
            float4 xv0 = *(const float4*)&as[(n0+0)*APAD + kb + k];
            float4 xv1 = *(const float4*)&as[(n0+1)*APAD + kb + k];
            float4 xv2 = *(const float4*)&as[(n0+2)*APAD + kb + k];
            float4 xv3 = *(const float4*)&as[(n0+3)*APAD + kb + k];
            float xa0[4] = {xv0.x, xv0.y, xv0.z, xv0.w};
            float xa1[4] = {xv1.x, xv1.y, xv1.z, xv1.w};
            float xa2[4] = {xv2.x, xv2.y, xv2.z, xv2.w};
            float xa3[4] = {xv3.x, xv3.y, xv3.z, xv3.w};
            #pragma unroll
            for (int kk = 0; kk < 4; ++kk){
                float4 wv = *(const float4*)&Ws[(k+kk)*H2 + j0];
                acc[0][0] += xa0[kk]*wv.x; acc[0][1] += xa0[kk]*wv.y; acc[0][2] += xa0[kk]*wv.z; acc[0][3] += xa0[kk]*wv.w;
                acc[1][0] += xa1[kk]*wv.x; acc[1][1] += xa1[kk]*wv.y; acc[1][2] += xa1[kk]*wv.z; acc[1][3] += xa1[kk]*wv.w;
                acc[2][0] += xa2[kk]*wv.x; acc[2][1] += xa2[kk]*wv.y; acc[2][2] += xa2[kk]*wv.z; acc[2][3] += xa2[kk]*wv.w;
                acc[3][0] += xa3[kk]*wv.x; acc[3][1] += xa3[kk]*wv.y; acc[3][2] += xa3[kk]*wv.z; acc[3][3] += xa3[kk]*wv.w;
            }
        }
        if (half == 0){
            __syncthreads();               // all done reading Ws half-0
            *(float4*)&Ws[(t      )*4] = w1a;
            *(float4*)&Ws[(t + 256)*4] = w1b;
            *(float4*)&Ws[(t + 512)*4] = w1c;
            *(float4*)&Ws[(t + 768)*4] = w1d;
            __syncthreads();               // Ws half-1 visible
        }
    }
    float p0 = pws[j0], p1 = pws[j0+1], p2 = pws[j0+2], p3 = pws[j0+3];
    float bj0 = b2[j0], bj1 = b2[j0+1], bj2 = b2[j0+2], bj3 = b2[j0+3];
    #pragma unroll
    for (int i = 0; i < 4; ++i){
        float v0 = acc[i][0] + bj0; v0 = v0 > 0.f ? v0 : 0.f;
        float v1 = acc[i][1] + bj1; v1 = v1 > 0.f ? v1 : 0.f;
        float v2 = acc[i][2] + bj2; v2 = v2 > 0.f ? v2 : 0.f;
        float v3 = acc[i][3] + bj3; v3 = v3 > 0.f ? v3 : 0.f;
        size_t base = (size_t)(node0 + n0 + i)*64 + tc*2;
        a2u[base]     = packbf(v0, v1);
        a2u[base + 1] = packbf(v2, v3);
        float sp = v0*p0 + v1*p1 + v2*p2 + v3*p3;
        sp += __shfl_xor(sp, 16, 32);
        sp += __shfl_xor(sp,  8, 32);
        sp += __shfl_xor(sp,  4, 32);
        sp += __shfl_xor(sp,  2, 32);
        sp += __shfl_xor(sp,  1, 32);
        if (tc == 0) score[node0 + n0 + i] = sp;   // raw (unscaled) dot
    }
}

// ---- K4: per-graph top-K pool + FC + log_softmax (shfl-bitonic) ----
__global__ __launch_bounds__(512) void k_pool(const u32* __restrict__ a2u,
                                              const float* __restrict__ score,
                                              const float* __restrict__ pw,
                                              const float* __restrict__ fcW,
                                              const float* __restrict__ fcb,
                                              float* __restrict__ out){
    __shared__ float so[NN];
    __shared__ float ss[NN];
    __shared__ float th[NN];
    __shared__ float pm[32*H2];    // 16 KB
    __shared__ float gl[H2];
    __shared__ float fws[H2*NC];   // 5 KB
    __shared__ float lg[NC];
    __shared__ float red[3];
    int bid = blockIdx.x, t = threadIdx.x;
    int b = ((bid & 7) << 4) | (bid >> 3);     // match gemm2s graph->XCD residue
    float sc = score[b*NN + t];                // prefetch at entry
    for (int i = t; i < H2*NC; i += 512) fws[i] = fcW[i];
    if (t < H2){ float v2 = pw[t]; gl[t] = v2*v2; }
    __syncthreads();
    if (t == 0){
        float s = 0.f;
        for (int i = 0; i < H2; ++i) s += gl[i];
        red[2] = rsqrtf(s);
    }
    __syncthreads();
    float pwinv = red[2];
    so[t] = sc; th[t] = tanhf(sc*pwinv);
    // bitonic sort descending, value in register v (j<64 via shfl)
    float v = sc;
    for (int k = 2; k <= NN; k <<= 1){
        for (int j = k >> 1; j > 0; j >>= 1){
            bool desc  = ((t & k) == 0);
            bool lower = ((t & j) == 0);
            bool wantmax = (desc == lower);
            float c;
            if (j >= 64){
                ss[t] = v; __syncthreads();
                c = ss[t ^ j];
                __syncthreads();
            } else {
                c = __shfl_xor(v, j, 64);
            }
            v = wantmax ? fmaxf(v, c) : fminf(v, c);
        }
    }
    ss[t] = v;
    __syncthreads();
    float thresh = ss[KSEL-1];
    float mask_t = (so[t] >= thresh) ? 0.f : -INFINITY;
    __syncthreads();
    so[t] = mask_t;
    __syncthreads();
    // gated max: lane tc handles feats {8tc..8tc+7} via uint4; group q: 16 nodes
    int tc = t & 15, q = t >> 4;
    const uint4* ap = (const uint4*)(a2u + (size_t)b*NN*64);
    float m0 = -INFINITY, m1 = -INFINITY, m2 = -INFINITY, m3 = -INFINITY;
    float m4 = -INFINITY, m5 = -INFINITY, m6 = -INFINITY, m7 = -INFINITY;
    int nb = q*16;
    #pragma unroll 4
    for (int n = nb; n < nb + 16; ++n){
        uint4 vv = ap[(size_t)n*16 + tc];
        float thn = th[n], son = so[n];
        m0 = fmaxf(m0, lo2f(vv.x)*thn + son);
        m1 = fmaxf(m1, hi2f(vv.x)*thn + son);
        m2 = fmaxf(m2, lo2f(vv.y)*thn + son);
        m3 = fmaxf(m3, hi2f(vv.y)*thn + son);
        m4 = fmaxf(m4, lo2f(vv.z)*thn + son);
        m5 = fmaxf(m5, hi2f(vv.z)*thn + son);
        m6 = fmaxf(m6, lo2f(vv.w)*thn + son);
        m7 = fmaxf(m7, hi2f(vv.w)*thn + son);
    }
    float* pmr = &pm[q*H2 + 8*tc];
    pmr[0] = m0; pmr[1] = m1; pmr[2] = m2; pmr[3] = m3;
    pmr[4] = m4; pmr[5] = m5; pmr[6] = m6; pmr[7] = m7;
    __syncthreads();
    if (t < H2){
        float g = pm[t];
        #pragma unroll
        for (int qq = 1; qq < 32; ++qq) g = fmaxf(g, pm[qq*H2 + t]);
        gl[t] = g;
    }
    __syncthreads();
    if (t < NC){
        float acc = fcb[t];
        for (int k2 = 0; k2 < H2; ++k2) acc += gl[k2]*fws[k2*NC + t];
        lg[t] = acc;
    }
    __syncthreads();
    if (t == 0){
        float mx = lg[0];
        for (int i = 1; i < NC; ++i) mx = fmaxf(mx, lg[i]);
        float s = 0.f;
        for (int i = 0; i < NC; ++i) s += expf(lg[i] - mx);
        red[0] = mx; red[1] = logf(s);
    }
    __syncthreads();
    if (t < NC) out[b*NC + t] = lg[t] - red[0] - red[1];
}

extern "C" void kernel_launch(void* const* d_in, const int* in_sizes, int n_in,
                              void* d_out, int out_size, void* d_ws, size_t ws_size,
                              hipStream_t stream) {
    const float* x   = (const float*)d_in[0];
    const int*   ei  = (const int*)d_in[1];
    // d_in[2] = batch (unused; batch = node / NN)
    const float* W1  = (const float*)d_in[3];
    const float* b1  = (const float*)d_in[4];
    const float* W2  = (const float*)d_in[5];
    const float* b2  = (const float*)d_in[6];
    const float* pw  = (const float*)d_in[7];
    const float* fcW = (const float*)d_in[8];
    const float* fcb = (const float*)d_in[9];

    char* ws = (char*)d_ws;
    int*   cnt   = (int*)(ws + 4096);            // 256 KB
    float* score = (float*)(ws + 524288);        // 256 KB
    int*   adj   = (int*)(ws + 4194304);         // NODES*48*4 = 12.6 MB
    u32*   h1u   = (u32*)(ws + 16777216);        // 8 MB
    u32*   a1u   = (u32*)(ws + 25165824);        // 8 MB
    u32*   a2u   = (u32*)(ws + 33554432);        // 16 MB

    hipMemsetAsync(cnt, 0, NODES*sizeof(int), stream);
    k_prep_gemm1<<<NODES/G1NODES, 512, 0, stream>>>(ei, x, W1, cnt, adj, h1u);
    k_agg1<<<NODES/32, 256, 0, stream>>>((const uint4*)h1u, cnt, adj,
                                         (const float4*)b1, (uint4*)a1u);
    k_gemm2s<<<NODES/G2NODES, 256, 0, stream>>>((const uint4*)a1u, cnt, adj,
                                                W2, b2, pw, a2u, score);
    k_pool<<<BB, 512, 0, stream>>>(a2u, score, pw, fcW, fcb, (float*)d_out);
}